// Round 13
// baseline (615.885 us; speedup 1.0000x reference)
//
#include <hip/hip_runtime.h>
#include <hip/hip_bf16.h>
#include <math.h>

#define F_IN  128
#define HIDC  256
#define NG    8
#define EPS_BN 1e-5f

typedef unsigned short u16;
typedef unsigned int   u32;
typedef unsigned char  u8;
typedef __attribute__((ext_vector_type(8))) short bf16x8;
typedef __attribute__((ext_vector_type(4))) float f32x4;
typedef __attribute__((ext_vector_type(2))) float f32x2;

// ---------- bf16 helpers ----------
static __device__ __forceinline__ float b2f(u16 u) {
    return __uint_as_float((u32)u << 16);
}
static __device__ __forceinline__ u16 f2b(float f) {   // RNE
    u32 u = __float_as_uint(f);
    u32 r = (u + 0x7fffu + ((u >> 16) & 1u)) >> 16;
    return (u16)r;
}
static __device__ __forceinline__ u32 pack2(float a, float b) {
    return (u32)f2b(a) | ((u32)f2b(b) << 16);
}
static __device__ __forceinline__ float lk(float v) {   // leaky relu 0.2
    return v >= 0.f ? v : 0.2f * v;
}
static __device__ __forceinline__ u8 f2fp8(float v) {  // e4m3 via HW cvt
    return (u8)__builtin_amdgcn_cvt_pk_fp8_f32(v, v, 0, false);
}

// W [K][256] row-major -> fragment-ordered WTf: index
// ((ntile*(K/32)+kstep)*64 + lane)*8 + j  =  W[kstep*32+(lane>>4)*8+j][ntile*16+(lane&15)]
static __device__ __forceinline__ u16 frag_elem(const float* __restrict__ W,
                                                int i, int K) {
    int j = i & 7;
    int lane = (i >> 3) & 63;
    int rest = i >> 9;
    int ksteps = K >> 5;
    int kst = rest % ksteps;
    int ntile = rest / ksteps;
    int k = kst * 32 + (lane >> 4) * 8 + j;
    int n = ntile * 16 + (lane & 15);
    return f2b(W[(long)k * HIDC + n]);
}

// ---------- prep: x->bf16 pairs + 3 weight fragment-swizzles --------------
__global__ void prep_kernel(const float* __restrict__ x,
                            const float* __restrict__ W1,
                            const float* __restrict__ W2,
                            const float* __restrict__ Wq1,
                            u32* __restrict__ xb, u16* __restrict__ WT1,
                            u16* __restrict__ WT2, u16* __restrict__ WQT,
                            int npair) {
    int i = blockIdx.x * 256 + threadIdx.x;
    if (i < npair) {
        float2 v = ((const float2*)x)[i];
        xb[i] = pack2(v.x, v.y);
        return;
    }
    i -= npair;
    if (i < F_IN * HIDC) { WT1[i] = frag_elem(W1, i, F_IN); return; }
    i -= F_IN * HIDC;
    if (i < HIDC * HIDC) { WT2[i] = frag_elem(W2, i, HIDC); return; }
    i -= HIDC * HIDC;
    if (i < HIDC * HIDC) { WQT[i] = frag_elem(Wq1, i, HIDC); }
}

// ---------- out init: q part = bq2 broadcast, tail = batch as float -------
__global__ void out_init_kernel(float* __restrict__ out,
                                const float* __restrict__ bq2,
                                const int* __restrict__ batch, int N) {
    int i = blockIdx.x * 256 + threadIdx.x;
    if (i < N * 4) out[i] = bq2[i & 3];
    else if (i < N * 5) out[i] = (float)batch[i - N * 4];
}

// ---------- BN coefficients: scale = g*rsqrt(var), bias = beta - mu*scale --
__global__ void bn_coef_kernel(const float* __restrict__ sum,
                               const float* __restrict__ sumsq,
                               const float* __restrict__ gamma,
                               const float* __restrict__ beta,
                               float* __restrict__ scale,
                               float* __restrict__ bias, int N) {
    int c = threadIdx.x;
    float invN = 1.f / (float)N;
    float mu = sum[c] * invN;
    float var = sumsq[c] * invN - mu * mu;
    float inv = rsqrtf(var + EPS_BN);
    float sc = gamma[c] * inv;
    scale[c] = sc;
    bias[c] = beta[c] - mu * sc;
}

// ---------- MFMA GEMM: fat blocks, 8 M-subtiles each (fixed-cost amortize)
// Block = 256 thr / 4 waves; wave owns a 64-col strip. Loop over 8 subtiles
// of 32 rows (256 rows/block) -> grid = ceil(M/256) = 196 blocks < 256 CUs:
// all blocks fully parallel, block fixed cost paid once, B stream repeats
// 8x (L1/L2-hot after subtile 0). A staged coalesced to LDS per subtile.
// MODE 0: plain A, C (fp8) + H=4 alpha logits (head = wave id).
// MODE 1: BN+relu A, C (fp8) + H=1 alpha logits (atomicAdd).
// MODE 2: BN+relu A, no C; fused head: q += relu(acc+gproj+bq1).Wq2.
template <int K, int MODE>
__global__ __launch_bounds__(256)
void gemm_mfma_kernel(const u16* __restrict__ A, const u16* __restrict__ WTf,
                      u8* __restrict__ C, int M,
                      const float* __restrict__ scaleA, const float* __restrict__ biasA,
                      const float* __restrict__ wsrc, const float* __restrict__ wdst,
                      float* __restrict__ asrc, float* __restrict__ adst,
                      const float* __restrict__ gproj, const int* __restrict__ bat,
                      const float* __restrict__ bq1,
                      const float* __restrict__ wq2, float* __restrict__ qout) {
    constexpr int KSTEPS = K / 32;
    constexpr int RCH = K / 8;                 // uint4 chunks per A row
    __shared__ u16 sA[32][K + 8];
    int tid = threadIdx.x;
    int wid = tid >> 6, lane = tid & 63;
    int row = lane & 15, quad = lane >> 4;
    int mbase = blockIdx.x * 256;
    const u16* Bbase = WTf + ((size_t)(wid * 4) * KSTEPS * 64 + lane) * 8;
    int n0 = wid * 64;

    for (int sub = 0; sub < 8; ++sub) {
        int m0 = mbase + sub * 32;
        if (m0 >= M) break;                    // block-uniform: barrier-safe

        __syncthreads();                       // prior subtile's sA reads done
        for (int i = tid; i < 32 * RCH; i += 256) {
            int r = i / RCH, c = i % RCH;
            int gm = m0 + r;
            gm = gm < M ? gm : M - 1;
            *(uint4*)&sA[r][c * 8] = *(const uint4*)(A + (size_t)gm * K + c * 8);
        }
        __syncthreads();

        int mf0 = m0, mf1 = m0 + 16;           // M % 16 == 0
        bool v1 = mf1 < M;                      // v0 always true here

        f32x4 acc[2][4];
#pragma unroll
        for (int f = 0; f < 2; ++f)
#pragma unroll
            for (int t = 0; t < 4; ++t) acc[f][t] = (f32x4){0.f, 0.f, 0.f, 0.f};

#pragma unroll
        for (int ks = 0; ks < KSTEPS; ++ks) {
            int kk = ks * 32 + quad * 8;
            bf16x8 a[2];
            a[0] = *(const bf16x8*)&sA[row][kk];
            a[1] = *(const bf16x8*)&sA[16 + row][kk];
            if constexpr (MODE != 0) {   // fused BN + relu on A fragments
                int c0 = kk;
                float4 s0 = *(const float4*)(scaleA + c0);
                float4 s1 = *(const float4*)(scaleA + c0 + 4);
                float4 b0 = *(const float4*)(biasA + c0);
                float4 b1 = *(const float4*)(biasA + c0 + 4);
#pragma unroll
                for (int f = 0; f < 2; ++f) {
                    float xv[8];
#pragma unroll
                    for (int j = 0; j < 8; ++j) xv[j] = b2f((u16)a[f][j]);
                    xv[0] = fmaxf(fmaf(s0.x, xv[0], b0.x), 0.f);
                    xv[1] = fmaxf(fmaf(s0.y, xv[1], b0.y), 0.f);
                    xv[2] = fmaxf(fmaf(s0.z, xv[2], b0.z), 0.f);
                    xv[3] = fmaxf(fmaf(s0.w, xv[3], b0.w), 0.f);
                    xv[4] = fmaxf(fmaf(s1.x, xv[4], b1.x), 0.f);
                    xv[5] = fmaxf(fmaf(s1.y, xv[5], b1.y), 0.f);
                    xv[6] = fmaxf(fmaf(s1.z, xv[6], b1.z), 0.f);
                    xv[7] = fmaxf(fmaf(s1.w, xv[7], b1.w), 0.f);
#pragma unroll
                    for (int j = 0; j < 8; ++j) a[f][j] = (short)f2b(xv[j]);
                }
            }
#pragma unroll
            for (int t = 0; t < 4; ++t) {
                bf16x8 b = *(const bf16x8*)(Bbase + ((size_t)t * KSTEPS + ks) * 512);
                acc[0][t] = __builtin_amdgcn_mfma_f32_16x16x32_bf16(a[0], b, acc[0][t], 0, 0, 0);
                acc[1][t] = __builtin_amdgcn_mfma_f32_16x16x32_bf16(a[1], b, acc[1][t], 0, 0, 0);
            }
        }

        int mf[2] = {mf0, mf1};
        bool vf[2] = {true, v1};
        if constexpr (MODE == 2) {   // fused head + q epilogue (no C store)
            float qacc[2][4][4];
#pragma unroll
            for (int f = 0; f < 2; ++f)
#pragma unroll
                for (int r = 0; r < 4; ++r)
#pragma unroll
                    for (int j = 0; j < 4; ++j) qacc[f][r][j] = 0.f;
#pragma unroll
            for (int f = 0; f < 2; ++f) {
                if (!vf[f]) continue;
                int bm[4];
#pragma unroll
                for (int r = 0; r < 4; ++r) bm[r] = bat[mf[f] + quad * 4 + r];
#pragma unroll
                for (int t = 0; t < 4; ++t) {
                    int n = n0 + t * 16 + row;
                    float bq = bq1[n];
                    float4 w4 = ((const float4*)wq2)[n];
#pragma unroll
                    for (int r = 0; r < 4; ++r) {
                        float v = fmaxf(acc[f][t][r] + gproj[bm[r] * HIDC + n] + bq, 0.f);
                        qacc[f][r][0] = fmaf(v, w4.x, qacc[f][r][0]);
                        qacc[f][r][1] = fmaf(v, w4.y, qacc[f][r][1]);
                        qacc[f][r][2] = fmaf(v, w4.z, qacc[f][r][2]);
                        qacc[f][r][3] = fmaf(v, w4.w, qacc[f][r][3]);
                    }
                }
            }
#pragma unroll
            for (int off = 1; off < 16; off <<= 1)
#pragma unroll
                for (int f = 0; f < 2; ++f)
#pragma unroll
                    for (int r = 0; r < 4; ++r)
#pragma unroll
                        for (int j = 0; j < 4; ++j)
                            qacc[f][r][j] += __shfl_xor(qacc[f][r][j], off, 64);
            if (row == 0) {
#pragma unroll
                for (int f = 0; f < 2; ++f) {
                    if (!vf[f]) continue;
#pragma unroll
                    for (int r = 0; r < 4; ++r) {
                        size_t m = mf[f] + quad * 4 + r;
#pragma unroll
                        for (int j = 0; j < 4; ++j)
                            atomicAdd(&qout[m * 4 + j], qacc[f][r][j]);
                    }
                }
            }
        } else {
#pragma unroll
            for (int f = 0; f < 2; ++f) {
                if (!vf[f]) continue;
#pragma unroll
                for (int t = 0; t < 4; ++t) {
                    int n = n0 + t * 16 + row;
#pragma unroll
                    for (int r = 0; r < 4; ++r)
                        C[(size_t)(mf[f] + quad * 4 + r) * HIDC + n] = f2fp8(acc[f][t][r]);
                }
            }
            if constexpr (MODE == 0) {   // H=4 logits; wave owns one head
                float pa[2][4] = {}, pd[2][4] = {};
#pragma unroll
                for (int t = 0; t < 4; ++t) {
                    float ws = wsrc[n0 + t * 16 + row];
                    float wd = wdst[n0 + t * 16 + row];
#pragma unroll
                    for (int f = 0; f < 2; ++f)
#pragma unroll
                        for (int r = 0; r < 4; ++r) {
                            pa[f][r] = fmaf(acc[f][t][r], ws, pa[f][r]);
                            pd[f][r] = fmaf(acc[f][t][r], wd, pd[f][r]);
                        }
                }
#pragma unroll
                for (int off = 1; off < 16; off <<= 1)
#pragma unroll
                    for (int f = 0; f < 2; ++f)
#pragma unroll
                        for (int r = 0; r < 4; ++r) {
                            pa[f][r] += __shfl_xor(pa[f][r], off, 64);
                            pd[f][r] += __shfl_xor(pd[f][r], off, 64);
                        }
                if (row == 0) {
#pragma unroll
                    for (int f = 0; f < 2; ++f) {
                        if (!vf[f]) continue;
#pragma unroll
                        for (int r = 0; r < 4; ++r) {
                            int m = mf[f] + quad * 4 + r;
                            asrc[m * 4 + wid] = pa[f][r];
                            adst[m * 4 + wid] = pd[f][r];
                        }
                    }
                }
            }
            if constexpr (MODE == 1) {   // H=1 logits; 4 waves sum via atomics
                float pa[2][4] = {}, pd[2][4] = {};
#pragma unroll
                for (int t = 0; t < 4; ++t) {
                    float ws = wsrc[n0 + t * 16 + row];
                    float wd = wdst[n0 + t * 16 + row];
#pragma unroll
                    for (int f = 0; f < 2; ++f)
#pragma unroll
                        for (int r = 0; r < 4; ++r) {
                            pa[f][r] = fmaf(acc[f][t][r], ws, pa[f][r]);
                            pd[f][r] = fmaf(acc[f][t][r], wd, pd[f][r]);
                        }
                }
#pragma unroll
                for (int off = 1; off < 16; off <<= 1)
#pragma unroll
                    for (int f = 0; f < 2; ++f)
#pragma unroll
                        for (int r = 0; r < 4; ++r) {
                            pa[f][r] += __shfl_xor(pa[f][r], off, 64);
                            pd[f][r] += __shfl_xor(pd[f][r], off, 64);
                        }
                if (row == 0) {
#pragma unroll
                    for (int f = 0; f < 2; ++f) {
                        if (!vf[f]) continue;
#pragma unroll
                        for (int r = 0; r < 4; ++r) {
                            int m = mf[f] + quad * 4 + r;
                            atomicAdd(&asrc[m], pa[f][r]);
                            atomicAdd(&adst[m], pd[f][r]);
                        }
                    }
                }
            }
        }
    }
}

// =================== CSR build (by destination), built once ===============
__global__ void deg_kernel(const int* __restrict__ ei, int E, int N,
                           int* __restrict__ deg) {
    int e = blockIdx.x * blockDim.x + threadIdx.x;
    if (e >= E + N) return;
    int d = (e < E) ? ei[E + e] : (e - E);
    atomicAdd(&deg[d], 1);
}

__global__ __launch_bounds__(256)
void scan_phase1(const int* __restrict__ deg, int* __restrict__ part,
                 int* __restrict__ bsum, int N) {
    __shared__ int tmp[256];
    int i = blockIdx.x * 256 + threadIdx.x;
    int v = (i < N) ? deg[i] : 0;
    tmp[threadIdx.x] = v;
    __syncthreads();
    for (int off = 1; off < 256; off <<= 1) {
        int t = (threadIdx.x >= off) ? tmp[threadIdx.x - off] : 0;
        __syncthreads();
        tmp[threadIdx.x] += t;
        __syncthreads();
    }
    if (i < N) part[i] = tmp[threadIdx.x];
    if (threadIdx.x == 255) bsum[blockIdx.x] = tmp[255];
}
__global__ __launch_bounds__(256)
void scan_phase2(int* __restrict__ bsum, int nb) {
    __shared__ int tmp[256];
    int v = (threadIdx.x < nb) ? bsum[threadIdx.x] : 0;
    tmp[threadIdx.x] = v;
    __syncthreads();
    for (int off = 1; off < 256; off <<= 1) {
        int t = (threadIdx.x >= off) ? tmp[threadIdx.x - off] : 0;
        __syncthreads();
        tmp[threadIdx.x] += t;
        __syncthreads();
    }
    if (threadIdx.x < nb)
        bsum[threadIdx.x] = threadIdx.x ? tmp[threadIdx.x - 1] : 0;
}
__global__ __launch_bounds__(256)
void scan_phase3(const int* __restrict__ part, const int* __restrict__ bsum,
                 int* __restrict__ rowptr, int N) {
    int i = blockIdx.x * 256 + threadIdx.x;
    if (i < N) rowptr[i + 1] = part[i] + bsum[blockIdx.x];
    if (i == 0) rowptr[0] = 0;
}

__global__ void fill_kernel(const int* __restrict__ ei, int E, int N,
                            const int* __restrict__ rowptr,
                            int* __restrict__ cur, int* __restrict__ csr_src) {
    int e = blockIdx.x * blockDim.x + threadIdx.x;
    if (e >= E + N) return;
    int s = (e < E) ? ei[e] : (e - E);
    int d = (e < E) ? ei[E + e] : (e - E);
    int pos = rowptr[d] + atomicAdd(&cur[d], 1);
    csr_src[pos] = s;
}

// ========== fused GAT edge-softmax + aggregation (deferred normalize) =====
template <int H>
__global__ __launch_bounds__(256)
void gat_gather_kernel(const int* __restrict__ rowptr,
                       const int* __restrict__ csr_src,
                       const float* __restrict__ asrc,
                       const float* __restrict__ adst,
                       const u8* __restrict__ h,
                       u16* __restrict__ agg, int N) {
    __shared__ __align__(16) uint2 s_ed[4][64 * H];
    int wid = threadIdx.x >> 6, lane = threadIdx.x & 63;
    int n = blockIdx.x * 4 + wid;
    if (n >= N) return;
    int start = rowptr[n], end = rowptr[n + 1];
    int deg = end - start;
    float ad[H];
#pragma unroll
    for (int hh = 0; hh < H; ++hh) ad[hh] = adst[n * H + hh];

    f32x2 acc01 = {0.f, 0.f}, acc23 = {0.f, 0.f};
    const int head = (H == 4) ? (lane >> 4) : 0;
    const u8* hb = h;
    const u32 laneB = (u32)lane * 4u;
    float wsum[H];

#define GBODY(J) {                                                             \
            uint2 e_ = s_ed[wid][(H == 4) ? ((J) * 4 + head) : (J)];           \
            u32 hv_ = *(const u32*)(hb + (size_t)(e_.x + laneB));              \
            float al_ = __uint_as_float(e_.y);                                 \
            f32x2 al2_ = {al_, al_};                                           \
            f32x2 v01_ = __builtin_amdgcn_cvt_pk_f32_fp8(hv_, false);          \
            f32x2 v23_ = __builtin_amdgcn_cvt_pk_f32_fp8(hv_, true);           \
            acc01 = __builtin_elementwise_fma(v01_, al2_, acc01);              \
            acc23 = __builtin_elementwise_fma(v23_, al2_, acc23); }

    if (deg <= 64) {
        float v[H];
#pragma unroll
        for (int hh = 0; hh < H; ++hh) v[hh] = -1e30f;
        u32 off = 0;
        if (lane < deg) {
            int s = csr_src[start + lane];
            off = (u32)s * (u32)HIDC;
            if (H == 4) {
                float4 a4 = *(const float4*)(asrc + s * 4);
                v[0] = lk(a4.x + ad[0]);
                v[1 % H] = lk(a4.y + ad[1 % H]);
                v[2 % H] = lk(a4.z + ad[2 % H]);
                v[3 % H] = lk(a4.w + ad[3 % H]);
            } else {
                v[0] = lk(asrc[s] + ad[0]);
            }
        }
        float m[H];
#pragma unroll
        for (int hh = 0; hh < H; ++hh) m[hh] = v[hh];
#pragma unroll
        for (int o = 1; o < 64; o <<= 1)
#pragma unroll
            for (int hh = 0; hh < H; ++hh)
                m[hh] = fmaxf(m[hh], __shfl_xor(m[hh], o, 64));
        float w[H];
#pragma unroll
        for (int hh = 0; hh < H; ++hh) {
            w[hh] = __expf(v[hh] - m[hh]);
            wsum[hh] = w[hh];
        }
#pragma unroll
        for (int o = 1; o < 64; o <<= 1)
#pragma unroll
            for (int hh = 0; hh < H; ++hh)
                wsum[hh] += __shfl_xor(wsum[hh], o, 64);
        if (H == 4) {
            uint4 w0, w1;
            w0.x = off; w0.y = __float_as_uint(w[0]);
            w0.z = off; w0.w = __float_as_uint(w[1 % H]);
            w1.x = off; w1.y = __float_as_uint(w[2 % H]);
            w1.z = off; w1.w = __float_as_uint(w[3 % H]);
            *(uint4*)&s_ed[wid][lane * 4] = w0;
            *(uint4*)&s_ed[wid][lane * 4 + 2] = w1;
        } else {
            s_ed[wid][lane] = make_uint2(off, __float_as_uint(w[0]));
        }
        int j = 0;
        for (; j + 4 <= deg; j += 4) { GBODY(j) GBODY(j + 1) GBODY(j + 2) GBODY(j + 3) }
        for (; j < deg; ++j) GBODY(j)
    } else {
        float m[H];
#pragma unroll
        for (int hh = 0; hh < H; ++hh) m[hh] = -1e30f;
        for (int i = start + lane; i < end; i += 64) {
            int s = csr_src[i];
            if (H == 4) {
                float4 a4 = *(const float4*)(asrc + s * 4);
                m[0] = fmaxf(m[0], lk(a4.x + ad[0]));
                m[1 % H] = fmaxf(m[1 % H], lk(a4.y + ad[1 % H]));
                m[2 % H] = fmaxf(m[2 % H], lk(a4.z + ad[2 % H]));
                m[3 % H] = fmaxf(m[3 % H], lk(a4.w + ad[3 % H]));
            } else {
                m[0] = fmaxf(m[0], lk(asrc[s] + ad[0]));
            }
        }
#pragma unroll
        for (int o = 1; o < 64; o <<= 1)
#pragma unroll
            for (int hh = 0; hh < H; ++hh)
                m[hh] = fmaxf(m[hh], __shfl_xor(m[hh], o, 64));
#pragma unroll
        for (int hh = 0; hh < H; ++hh) wsum[hh] = 0.f;
        for (int base = start; base < end; base += 64) {
            int cnt = min(64, end - base);
            if (lane < cnt) {
                int s = csr_src[base + lane];
                u32 off = (u32)s * (u32)HIDC;
                if (H == 4) {
                    float4 a4 = *(const float4*)(asrc + s * 4);
                    float w0f = __expf(lk(a4.x + ad[0]) - m[0]);
                    float w1f = __expf(lk(a4.y + ad[1 % H]) - m[1 % H]);
                    float w2f = __expf(lk(a4.z + ad[2 % H]) - m[2 % H]);
                    float w3f = __expf(lk(a4.w + ad[3 % H]) - m[3 % H]);
                    wsum[0] += w0f; wsum[1 % H] += w1f;
                    wsum[2 % H] += w2f; wsum[3 % H] += w3f;
                    uint4 w0, w1;
                    w0.x = off; w0.y = __float_as_uint(w0f);
                    w0.z = off; w0.w = __float_as_uint(w1f);
                    w1.x = off; w1.y = __float_as_uint(w2f);
                    w1.z = off; w1.w = __float_as_uint(w3f);
                    *(uint4*)&s_ed[wid][lane * 4] = w0;
                    *(uint4*)&s_ed[wid][lane * 4 + 2] = w1;
                } else {
                    float wf = __expf(lk(asrc[s] + ad[0]) - m[0]);
                    wsum[0] += wf;
                    s_ed[wid][lane] = make_uint2(off, __float_as_uint(wf));
                }
            }
            int j = 0;
            for (; j + 4 <= cnt; j += 4) { GBODY(j) GBODY(j + 1) GBODY(j + 2) GBODY(j + 3) }
            for (; j < cnt; ++j) GBODY(j)
        }
#pragma unroll
        for (int o = 1; o < 64; o <<= 1)
#pragma unroll
            for (int hh = 0; hh < H; ++hh)
                wsum[hh] += __shfl_xor(wsum[hh], o, 64);
    }
#undef GBODY
    float sc = 1.f / (wsum[head] + 1e-16f);
    f32x2 sc2 = {sc, sc};
    acc01 *= sc2;
    acc23 *= sc2;
    uint2 o;
    o.x = pack2(acc01.x, acc01.y);
    o.y = pack2(acc23.x, acc23.y);
    ((uint2*)(agg + (size_t)n * HIDC))[lane] = o;
}

// ---------- BatchNorm stats (bf16 in, fp32 accumulate) ----------
__global__ __launch_bounds__(256)
void bn_stats_kernel(const u16* __restrict__ h, int N,
                     float* __restrict__ sum, float* __restrict__ sumsq) {
    int c = threadIdx.x;
    int r0 = blockIdx.x * 128;
    int rend = min(r0 + 128, N);
    float s = 0.f, q = 0.f;
    for (int r = r0; r < rend; ++r) {
        float v = b2f(h[(long)r * HIDC + c]);
        s += v;
        q += v * v;
    }
    atomicAdd(&sum[c], s);
    atomicAdd(&sumsq[c], q);
}

// ---------- graph mean pooling with inline BN+relu (batch sorted) ---------
__global__ __launch_bounds__(256)
void pool_bn_kernel(const u16* __restrict__ h, const int* __restrict__ batch,
                    int N, const float* __restrict__ scale,
                    const float* __restrict__ bias,
                    float* __restrict__ gsum, float* __restrict__ gcnt) {
    int c = threadIdx.x;
    float sc = scale[c], bi = bias[c];
    int r0 = blockIdx.x * 128;
    int rend = min(r0 + 128, N);
    int curb = -1;
    float acc = 0.f;
    for (int r = r0; r < rend; ++r) {
        int b = batch[r];
        if (b != curb) {
            if (curb >= 0) atomicAdd(&gsum[curb * HIDC + c], acc);
            curb = b; acc = 0.f;
        }
        acc += fmaxf(fmaf(sc, b2f(h[(long)r * HIDC + c]), bi), 0.f);
    }
    if (curb >= 0) atomicAdd(&gsum[curb * HIDC + c], acc);
    if (c == 0) {
        int prev = -1; float cnt = 0.f;
        for (int r = r0; r < rend; ++r) {
            int b = batch[r];
            if (b != prev) {
                if (prev >= 0) atomicAdd(&gcnt[prev], cnt);
                prev = b; cnt = 0.f;
            }
            cnt += 1.f;
        }
        if (prev >= 0) atomicAdd(&gcnt[prev], cnt);
    }
}

// ---------- gmean + projection: gproj[b,c] = Σ_k gmean[b,k]*Wq1[256+k,c] --
__global__ __launch_bounds__(256)
void gmean_gproj_kernel(const float* __restrict__ gsum,
                        const float* __restrict__ gcnt,
                        const float* __restrict__ Wq1,
                        float* __restrict__ gproj) {
    int b = blockIdx.x, c = threadIdx.x;
    __shared__ float gm[HIDC];
    gm[c] = gsum[b * HIDC + c] / fmaxf(gcnt[b], 1.f);
    __syncthreads();
    float acc = 0.f;
    for (int k = 0; k < HIDC; ++k)
        acc = fmaf(gm[k], Wq1[(long)(HIDC + k) * HIDC + c], acc);
    gproj[b * HIDC + c] = acc;
}

extern "C" void kernel_launch(void* const* d_in, const int* in_sizes, int n_in,
                              void* d_out, int out_size, void* d_ws, size_t ws_size,
                              hipStream_t stream) {
    const float* x   = (const float*)d_in[0];
    const int*   ei  = (const int*)d_in[1];
    const int*   bat = (const int*)d_in[2];
    const float* W1  = (const float*)d_in[3];
    const float* as1 = (const float*)d_in[4];
    const float* ad1 = (const float*)d_in[5];
    const float* g1  = (const float*)d_in[7];
    const float* be1 = (const float*)d_in[8];
    const float* W2  = (const float*)d_in[9];
    const float* as2 = (const float*)d_in[10];
    const float* ad2 = (const float*)d_in[11];
    const float* g2  = (const float*)d_in[13];
    const float* be2 = (const float*)d_in[14];
    const float* Wq1 = (const float*)d_in[15];
    const float* bq1 = (const float*)d_in[16];
    const float* Wq2 = (const float*)d_in[17];
    const float* bq2 = (const float*)d_in[18];
    float* out = (float*)d_out;

    const int N = in_sizes[0] / F_IN;   // 50000
    const int E = in_sizes[1] / 2;      // 800000
    const int Etot = E + N;
    const int nb = (N + 255) / 256;

    const size_t hbytes = (size_t)N * HIDC * sizeof(u16);   // 25.6 MB (bf16)
    char* p = (char*)d_ws;
    auto alloc = [&](size_t sz) { char* q = p; p += (sz + 255) & ~(size_t)255; return q; };
    u16* BX   = (u16*)alloc((size_t)N * F_IN * sizeof(u16)); // bf16 x
    u8*  BH   = (u8*)alloc((size_t)N * HIDC);  // h1 -> h2 (fp8, 12.8 MB)
    u16* BA   = (u16*)alloc(hbytes);   // agg1 -> agg2 (bf16)
    u16* WT1  = (u16*)alloc((size_t)HIDC * F_IN * sizeof(u16));
    u16* WT2  = (u16*)alloc((size_t)HIDC * HIDC * sizeof(u16));
    u16* WQT  = (u16*)alloc((size_t)HIDC * HIDC * sizeof(u16));
    // pairs sharing one memset are single allocations (alloc rounds to 256B!)
    float* asrc = (float*)alloc((size_t)N * 4 * 4 * 2);      // asrc | adst
    float* adst = asrc + (size_t)N * 4;
    int* rowptr  = (int*)alloc((size_t)(N + 1) * 4);
    int* csr_src = (int*)alloc((size_t)Etot * 4);
    int* cur     = (int*)alloc((size_t)N * 4 * 2);           // deg | fill cursor
    int* cur2    = cur + N;
    int* part    = (int*)alloc((size_t)N * 4);
    int* bsum    = (int*)alloc((size_t)nb * 4);
    float* bnsum = (float*)alloc(HIDC * 4 * 2);              // bnsum | bnsq
    float* bnsq  = bnsum + HIDC;
    float* sc1   = (float*)alloc(HIDC * 4);
    float* bi1   = (float*)alloc(HIDC * 4);
    float* sc2   = (float*)alloc(HIDC * 4);
    float* bi2   = (float*)alloc(HIDC * 4);
    float* gsum  = (float*)alloc((NG * HIDC + NG) * 4);      // gsum | gcnt
    float* gcnt  = gsum + NG * HIDC;
    float* gproj = (float*)alloc(NG * HIDC * 4);

    dim3 gemmGrid((N + 255) / 256);      // fat blocks: 256 rows x 256 cols
    int edgeBlocks = (Etot + 255) / 256;
    int nodeBlocksW = (N + 3) / 4;
    int npair = N * F_IN / 2;
    int prepTotal = npair + F_IN * HIDC + 2 * HIDC * HIDC;

    // ===================== CSR build (once) ==============================
    hipMemsetAsync(cur, 0, (size_t)N * 4 * 2, stream);        // cur + cur2
    deg_kernel<<<edgeBlocks, 256, 0, stream>>>(ei, E, N, cur);
    scan_phase1<<<nb, 256, 0, stream>>>(cur, part, bsum, N);
    scan_phase2<<<1, 256, 0, stream>>>(bsum, nb);
    scan_phase3<<<nb, 256, 0, stream>>>(part, bsum, rowptr, N);
    fill_kernel<<<edgeBlocks, 256, 0, stream>>>(ei, E, N, rowptr, cur2, csr_src);

    // ===================== prep (1 dispatch) =============================
    prep_kernel<<<(prepTotal + 255) / 256, 256, 0, stream>>>(
        x, W1, W2, Wq1, (u32*)BX, WT1, WT2, WQT, npair);

    // ===================== Layer 1: GEMM(+alpha4) -> gather -> BN stats ==
    gemm_mfma_kernel<F_IN, 0><<<gemmGrid, 256, 0, stream>>>(
        BX, WT1, BH, N, nullptr, nullptr, as1, ad1, asrc, adst,
        nullptr, nullptr, nullptr, nullptr, nullptr);
    gat_gather_kernel<4><<<nodeBlocksW, 256, 0, stream>>>(rowptr, csr_src, asrc, adst, BH, BA, N);
    hipMemsetAsync(bnsum, 0, HIDC * 4 * 2, stream);           // bnsum + bnsq
    bn_stats_kernel<<<(N + 127) / 128, 256, 0, stream>>>(BA, N, bnsum, bnsq);
    bn_coef_kernel<<<1, HIDC, 0, stream>>>(bnsum, bnsq, g1, be1, sc1, bi1, N);

    // ===================== Layer 2: GEMM(BN-A, +alpha1) -> gather -> BN ==
    hipMemsetAsync(asrc, 0, (size_t)N * 4 * 4 * 2, stream);   // asrc + adst
    gemm_mfma_kernel<HIDC, 1><<<gemmGrid, 256, 0, stream>>>(
        BA, WT2, BH, N, sc1, bi1, as2, ad2, asrc, adst,
        nullptr, nullptr, nullptr, nullptr, nullptr);
    gat_gather_kernel<1><<<nodeBlocksW, 256, 0, stream>>>(rowptr, csr_src, asrc, adst, BH, BA, N);
    hipMemsetAsync(bnsum, 0, HIDC * 4 * 2, stream);
    bn_stats_kernel<<<(N + 127) / 128, 256, 0, stream>>>(BA, N, bnsum, bnsq);
    bn_coef_kernel<<<1, HIDC, 0, stream>>>(bnsum, bnsq, g2, be2, sc2, bi2, N);

    // ===================== Pool (BN inline) + projection + out init ======
    hipMemsetAsync(gsum, 0, (NG * HIDC + NG) * 4, stream);    // gsum + gcnt
    pool_bn_kernel<<<(N + 127) / 128, 256, 0, stream>>>(BA, bat, N, sc2, bi2, gsum, gcnt);
    gmean_gproj_kernel<<<NG, HIDC, 0, stream>>>(gsum, gcnt, Wq1, gproj);
    out_init_kernel<<<(N * 5 + 255) / 256, 256, 0, stream>>>(out, bq2, bat, N);

    // ===================== Head: GEMM(BN-A, fused q epilogue) ============
    gemm_mfma_kernel<HIDC, 2><<<gemmGrid, 256, 0, stream>>>(
        BA, WQT, nullptr, N, sc2, bi2, nullptr, nullptr, nullptr, nullptr,
        gproj, bat, bq1, Wq2, out);
}

// Round 14
// 481.734 us; speedup vs baseline: 1.2785x; 1.2785x over previous
//
#include <hip/hip_runtime.h>
#include <hip/hip_bf16.h>
#include <math.h>

#define F_IN  128
#define HIDC  256
#define NG    8
#define EPS_BN 1e-5f

typedef unsigned short u16;
typedef unsigned int   u32;
typedef unsigned char  u8;
typedef __attribute__((ext_vector_type(8))) short bf16x8;
typedef __attribute__((ext_vector_type(4))) float f32x4;
typedef __attribute__((ext_vector_type(2))) float f32x2;

// ---------- bf16 helpers ----------
static __device__ __forceinline__ float b2f(u16 u) {
    return __uint_as_float((u32)u << 16);
}
static __device__ __forceinline__ u16 f2b(float f) {   // RNE
    u32 u = __float_as_uint(f);
    u32 r = (u + 0x7fffu + ((u >> 16) & 1u)) >> 16;
    return (u16)r;
}
static __device__ __forceinline__ u32 pack2(float a, float b) {
    return (u32)f2b(a) | ((u32)f2b(b) << 16);
}
static __device__ __forceinline__ float lk(float v) {   // leaky relu 0.2
    return v >= 0.f ? v : 0.2f * v;
}

// W [K][256] row-major -> fragment-ordered WTf: index
// ((ntile*(K/32)+kstep)*64 + lane)*8 + j  =  W[kstep*32+(lane>>4)*8+j][ntile*16+(lane&15)]
static __device__ __forceinline__ u16 frag_elem(const float* __restrict__ W,
                                                int i, int K) {
    int j = i & 7;
    int lane = (i >> 3) & 63;
    int rest = i >> 9;
    int ksteps = K >> 5;
    int kst = rest % ksteps;
    int ntile = rest / ksteps;
    int k = kst * 32 + (lane >> 4) * 8 + j;
    int n = ntile * 16 + (lane & 15);
    return f2b(W[(long)k * HIDC + n]);
}

// ---------- prep: x->bf16 pairs + 3 weight fragment-swizzles --------------
__global__ void prep_kernel(const float* __restrict__ x,
                            const float* __restrict__ W1,
                            const float* __restrict__ W2,
                            const float* __restrict__ Wq1,
                            u32* __restrict__ xb, u16* __restrict__ WT1,
                            u16* __restrict__ WT2, u16* __restrict__ WQT,
                            int npair) {
    int i = blockIdx.x * 256 + threadIdx.x;
    if (i < npair) {
        float2 v = ((const float2*)x)[i];
        xb[i] = pack2(v.x, v.y);
        return;
    }
    i -= npair;
    if (i < F_IN * HIDC) { WT1[i] = frag_elem(W1, i, F_IN); return; }
    i -= F_IN * HIDC;
    if (i < HIDC * HIDC) { WT2[i] = frag_elem(W2, i, HIDC); return; }
    i -= HIDC * HIDC;
    if (i < HIDC * HIDC) { WQT[i] = frag_elem(Wq1, i, HIDC); }
}

// ---------- MFMA GEMM, operand-swapped: D[n][m] layout --------------------
// Block = 32 rows x 256 cols, 4 waves = 4 col strips of 64; grid 1563.
// a-frag (slot1, j=m): A[m0+g*16+(lane&15)][k]; w-frag (slot0, i=n): frag-
// ordered WTf. acc[g][t][r] = C[m0+g*16+(lane&15)][wid*64+t*16+quad*4+r]:
// 4 consecutive N per lane -> C store is ONE packed-u32 fp8 store; logit/q
// reductions are 2-step butterflies (xor 16/32) over quads.
// MODE 0: plain A, C (fp8) + H=4 alpha logits (head = wave id, direct).
// MODE 1: BN(LDS-coef)+relu A, C (fp8) + H=1 logits (LDS cross-wave, direct).
// MODE 2: BN+relu A, no C; q = relu(acc+gproj+bq1).Wq2 + bq2 (direct store).
template <int K, int MODE>
__global__ __launch_bounds__(256)
void gemm_mfma_kernel(const u16* __restrict__ A, const u16* __restrict__ WTf,
                      u8* __restrict__ C, int M,
                      const float* __restrict__ bnsum, const float* __restrict__ bnsq,
                      const float* __restrict__ gamma, const float* __restrict__ beta,
                      const float* __restrict__ wsrc, const float* __restrict__ wdst,
                      float* __restrict__ asrc, float* __restrict__ adst,
                      const float* __restrict__ gproj, const int* __restrict__ bat,
                      const float* __restrict__ bq1,
                      const float* __restrict__ wq2, const float* __restrict__ bq2,
                      float* __restrict__ qout) {
    constexpr int KSTEPS = K / 32;
    constexpr int RCH = K / 8;                 // uint4 chunks per A row
    __shared__ u16 sA[32][K + 8];
    __shared__ __align__(16) float sCoef[HIDC];
    __shared__ __align__(16) float sBias[HIDC];
    __shared__ __align__(16) float sExtra[512];   // cross-wave reductions
    int tid = threadIdx.x;
    int m0 = blockIdx.x * 32;

    if constexpr (MODE != 0) {     // fused bn_coef: per-channel scale/bias
        float invN = 1.f / (float)M;
        float mu = bnsum[tid] * invN;
        float var = bnsq[tid] * invN - mu * mu;
        float inv = rsqrtf(var + EPS_BN);
        float sc = gamma[tid] * inv;
        sCoef[tid] = sc;
        sBias[tid] = beta[tid] - mu * sc;
    }
    // stage A tile: 32 rows x K, fully coalesced (rows clamped at tail)
    for (int i = tid; i < 32 * RCH; i += 256) {
        int r = i / RCH, c = i % RCH;
        int gm = m0 + r;
        gm = gm < M ? gm : M - 1;
        *(uint4*)&sA[r][c * 8] = *(const uint4*)(A + (size_t)gm * K + c * 8);
    }
    __syncthreads();

    int wid = tid >> 6, lane = tid & 63;
    int row = lane & 15, quad = lane >> 4;
    bool v1 = (m0 + 16) < M;                    // g=0 always valid
    int wave_n0 = wid * 64;

    f32x4 acc[2][4];
#pragma unroll
    for (int g = 0; g < 2; ++g)
#pragma unroll
        for (int t = 0; t < 4; ++t) acc[g][t] = (f32x4){0.f, 0.f, 0.f, 0.f};

    const u16* Bbase = WTf + ((size_t)(wid * 4) * KSTEPS * 64 + lane) * 8;

#pragma unroll
    for (int ks = 0; ks < KSTEPS; ++ks) {
        int kk = ks * 32 + quad * 8;
        bf16x8 a[2];
        a[0] = *(const bf16x8*)&sA[row][kk];
        a[1] = *(const bf16x8*)&sA[16 + row][kk];
        if constexpr (MODE != 0) {   // fused BN + relu on A fragments
            float4 s0 = *(const float4*)&sCoef[kk];
            float4 s1 = *(const float4*)&sCoef[kk + 4];
            float4 b0 = *(const float4*)&sBias[kk];
            float4 b1 = *(const float4*)&sBias[kk + 4];
#pragma unroll
            for (int g = 0; g < 2; ++g) {
                float xv[8];
#pragma unroll
                for (int j = 0; j < 8; ++j) xv[j] = b2f((u16)a[g][j]);
                xv[0] = fmaxf(fmaf(s0.x, xv[0], b0.x), 0.f);
                xv[1] = fmaxf(fmaf(s0.y, xv[1], b0.y), 0.f);
                xv[2] = fmaxf(fmaf(s0.z, xv[2], b0.z), 0.f);
                xv[3] = fmaxf(fmaf(s0.w, xv[3], b0.w), 0.f);
                xv[4] = fmaxf(fmaf(s1.x, xv[4], b1.x), 0.f);
                xv[5] = fmaxf(fmaf(s1.y, xv[5], b1.y), 0.f);
                xv[6] = fmaxf(fmaf(s1.z, xv[6], b1.z), 0.f);
                xv[7] = fmaxf(fmaf(s1.w, xv[7], b1.w), 0.f);
#pragma unroll
                for (int j = 0; j < 8; ++j) a[g][j] = (short)f2b(xv[j]);
            }
        }
#pragma unroll
        for (int t = 0; t < 4; ++t) {
            bf16x8 b = *(const bf16x8*)(Bbase + ((size_t)t * KSTEPS + ks) * 512);
            // swapped operands: D[n][m]
            acc[0][t] = __builtin_amdgcn_mfma_f32_16x16x32_bf16(b, a[0], acc[0][t], 0, 0, 0);
            acc[1][t] = __builtin_amdgcn_mfma_f32_16x16x32_bf16(b, a[1], acc[1][t], 0, 0, 0);
        }
    }

    bool vf[2] = {true, v1};
    if constexpr (MODE == 2) {       // fused head + q epilogue (no C store)
        float qa[2][4];
#pragma unroll
        for (int g = 0; g < 2; ++g)
#pragma unroll
            for (int j = 0; j < 4; ++j) qa[g][j] = 0.f;
        int bm[2];
#pragma unroll
        for (int g = 0; g < 2; ++g) {
            int m = m0 + g * 16 + row;
            bm[g] = bat[m < M ? m : M - 1];
        }
#pragma unroll
        for (int t = 0; t < 4; ++t) {
            int nb = wave_n0 + t * 16 + quad * 4;
            float4 bq4 = *(const float4*)&bq1[nb];
            float4 w4[4];
#pragma unroll
            for (int r = 0; r < 4; ++r) w4[r] = ((const float4*)wq2)[nb + r];
#pragma unroll
            for (int g = 0; g < 2; ++g) {
                float4 gp4 = *(const float4*)&gproj[bm[g] * HIDC + nb];
                float gp[4] = {gp4.x, gp4.y, gp4.z, gp4.w};
                float bqv[4] = {bq4.x, bq4.y, bq4.z, bq4.w};
#pragma unroll
                for (int r = 0; r < 4; ++r) {
                    float v = fmaxf(acc[g][t][r] + gp[r] + bqv[r], 0.f);
                    qa[g][0] = fmaf(v, w4[r].x, qa[g][0]);
                    qa[g][1] = fmaf(v, w4[r].y, qa[g][1]);
                    qa[g][2] = fmaf(v, w4[r].z, qa[g][2]);
                    qa[g][3] = fmaf(v, w4[r].w, qa[g][3]);
                }
            }
        }
#pragma unroll
        for (int off = 16; off < 64; off <<= 1)
#pragma unroll
            for (int g = 0; g < 2; ++g)
#pragma unroll
                for (int j = 0; j < 4; ++j)
                    qa[g][j] += __shfl_xor(qa[g][j], off, 64);
        if (quad == 0) {
#pragma unroll
            for (int g = 0; g < 2; ++g) {
                float4 v4 = {qa[g][0], qa[g][1], qa[g][2], qa[g][3]};
                *(float4*)&sExtra[((wid * 2 + g) * 16 + row) * 4] = v4;
            }
        }
        __syncthreads();
        if (tid < 128) {
            int g = tid >> 6, mm = (tid >> 2) & 15, j = tid & 3;
            float v = 0.f;
#pragma unroll
            for (int w = 0; w < 4; ++w)
                v += sExtra[((w * 2 + g) * 16 + mm) * 4 + j];
            int m = m0 + g * 16 + mm;
            if (m < M) qout[(size_t)m * 4 + j] = v + bq2[j];
        }
    } else {
        // C store: 4 consecutive n per lane -> one packed u32 of fp8
#pragma unroll
        for (int g = 0; g < 2; ++g) {
            if (!vf[g]) continue;
            int m = m0 + g * 16 + row;
#pragma unroll
            for (int t = 0; t < 4; ++t) {
                u32 pk = __builtin_amdgcn_cvt_pk_fp8_f32(acc[g][t][0], acc[g][t][1], 0, false);
                pk = __builtin_amdgcn_cvt_pk_fp8_f32(acc[g][t][2], acc[g][t][3], pk, true);
                *(u32*)&C[(size_t)m * HIDC + wave_n0 + t * 16 + quad * 4] = pk;
            }
        }
        float pa[2] = {0.f, 0.f}, pd[2] = {0.f, 0.f};
#pragma unroll
        for (int t = 0; t < 4; ++t) {
            int nb = wave_n0 + t * 16 + quad * 4;
            float4 ws4 = *(const float4*)&wsrc[nb];
            float4 wd4 = *(const float4*)&wdst[nb];
#pragma unroll
            for (int g = 0; g < 2; ++g) {
                pa[g] = fmaf(acc[g][t][0], ws4.x, pa[g]);
                pa[g] = fmaf(acc[g][t][1], ws4.y, pa[g]);
                pa[g] = fmaf(acc[g][t][2], ws4.z, pa[g]);
                pa[g] = fmaf(acc[g][t][3], ws4.w, pa[g]);
                pd[g] = fmaf(acc[g][t][0], wd4.x, pd[g]);
                pd[g] = fmaf(acc[g][t][1], wd4.y, pd[g]);
                pd[g] = fmaf(acc[g][t][2], wd4.z, pd[g]);
                pd[g] = fmaf(acc[g][t][3], wd4.w, pd[g]);
            }
        }
#pragma unroll
        for (int off = 16; off < 64; off <<= 1)
#pragma unroll
            for (int g = 0; g < 2; ++g) {
                pa[g] += __shfl_xor(pa[g], off, 64);
                pd[g] += __shfl_xor(pd[g], off, 64);
            }
        if constexpr (MODE == 0) {   // H=4: wave = head, direct store
            if (quad == 0) {
#pragma unroll
                for (int g = 0; g < 2; ++g) {
                    if (!vf[g]) continue;
                    int m = m0 + g * 16 + row;
                    asrc[m * 4 + wid] = pa[g];
                    adst[m * 4 + wid] = pd[g];
                }
            }
        }
        if constexpr (MODE == 1) {   // H=1: cross-wave LDS reduce, direct
            if (quad == 0) {
#pragma unroll
                for (int g = 0; g < 2; ++g) {
                    sExtra[((wid * 2 + g) * 2 + 0) * 16 + row] = pa[g];
                    sExtra[((wid * 2 + g) * 2 + 1) * 16 + row] = pd[g];
                }
            }
            __syncthreads();
            if (tid < 64) {
                int s = tid >> 5, g = (tid >> 4) & 1, mm = tid & 15;
                float v = 0.f;
#pragma unroll
                for (int w = 0; w < 4; ++w)
                    v += sExtra[((w * 2 + g) * 2 + s) * 16 + mm];
                int m = m0 + g * 16 + mm;
                if (m < M) (s == 0 ? asrc : adst)[m] = v;
            }
        }
    }
}

// =================== CSR build (by destination), built once ===============
__global__ void deg_kernel(const int* __restrict__ ei, int E, int N,
                           int* __restrict__ deg) {
    int e = blockIdx.x * blockDim.x + threadIdx.x;
    if (e >= E + N) return;
    int d = (e < E) ? ei[E + e] : (e - E);
    atomicAdd(&deg[d], 1);
}

__global__ __launch_bounds__(256)
void scan_phase1(const int* __restrict__ deg, int* __restrict__ part,
                 int* __restrict__ bsum, int N) {
    __shared__ int tmp[256];
    int i = blockIdx.x * 256 + threadIdx.x;
    int v = (i < N) ? deg[i] : 0;
    tmp[threadIdx.x] = v;
    __syncthreads();
    for (int off = 1; off < 256; off <<= 1) {
        int t = (threadIdx.x >= off) ? tmp[threadIdx.x - off] : 0;
        __syncthreads();
        tmp[threadIdx.x] += t;
        __syncthreads();
    }
    if (i < N) part[i] = tmp[threadIdx.x];
    if (threadIdx.x == 255) bsum[blockIdx.x] = tmp[255];
}
__global__ __launch_bounds__(256)
void scan_phase2(int* __restrict__ bsum, int nb) {
    __shared__ int tmp[256];
    int v = (threadIdx.x < nb) ? bsum[threadIdx.x] : 0;
    tmp[threadIdx.x] = v;
    __syncthreads();
    for (int off = 1; off < 256; off <<= 1) {
        int t = (threadIdx.x >= off) ? tmp[threadIdx.x - off] : 0;
        __syncthreads();
        tmp[threadIdx.x] += t;
        __syncthreads();
    }
    if (threadIdx.x < nb)
        bsum[threadIdx.x] = threadIdx.x ? tmp[threadIdx.x - 1] : 0;
}
__global__ __launch_bounds__(256)
void scan_phase3(const int* __restrict__ part, const int* __restrict__ bsum,
                 int* __restrict__ rowptr, int N) {
    int i = blockIdx.x * 256 + threadIdx.x;
    if (i < N) rowptr[i + 1] = part[i] + bsum[blockIdx.x];
    if (i == 0) rowptr[0] = 0;
}

__global__ void fill_kernel(const int* __restrict__ ei, int E, int N,
                            const int* __restrict__ rowptr,
                            int* __restrict__ cur, int* __restrict__ csr_src) {
    int e = blockIdx.x * blockDim.x + threadIdx.x;
    if (e >= E + N) return;
    int s = (e < E) ? ei[e] : (e - E);
    int d = (e < E) ? ei[E + e] : (e - E);
    int pos = rowptr[d] + atomicAdd(&cur[d], 1);
    csr_src[pos] = s;
}

// ========== fused GAT edge-softmax + aggregation (deferred normalize) =====
template <int H>
__global__ __launch_bounds__(256)
void gat_gather_kernel(const int* __restrict__ rowptr,
                       const int* __restrict__ csr_src,
                       const float* __restrict__ asrc,
                       const float* __restrict__ adst,
                       const u8* __restrict__ h,
                       u16* __restrict__ agg, int N) {
    __shared__ __align__(16) uint2 s_ed[4][64 * H];
    int wid = threadIdx.x >> 6, lane = threadIdx.x & 63;
    int n = blockIdx.x * 4 + wid;
    if (n >= N) return;
    int start = rowptr[n], end = rowptr[n + 1];
    int deg = end - start;
    float ad[H];
#pragma unroll
    for (int hh = 0; hh < H; ++hh) ad[hh] = adst[n * H + hh];

    f32x2 acc01 = {0.f, 0.f}, acc23 = {0.f, 0.f};
    const int head = (H == 4) ? (lane >> 4) : 0;
    const u8* hb = h;
    const u32 laneB = (u32)lane * 4u;
    float wsum[H];

#define GBODY(J) {                                                             \
            uint2 e_ = s_ed[wid][(H == 4) ? ((J) * 4 + head) : (J)];           \
            u32 hv_ = *(const u32*)(hb + (size_t)(e_.x + laneB));              \
            float al_ = __uint_as_float(e_.y);                                 \
            f32x2 al2_ = {al_, al_};                                           \
            f32x2 v01_ = __builtin_amdgcn_cvt_pk_f32_fp8(hv_, false);          \
            f32x2 v23_ = __builtin_amdgcn_cvt_pk_f32_fp8(hv_, true);           \
            acc01 = __builtin_elementwise_fma(v01_, al2_, acc01);              \
            acc23 = __builtin_elementwise_fma(v23_, al2_, acc23); }

    if (deg <= 64) {
        float v[H];
#pragma unroll
        for (int hh = 0; hh < H; ++hh) v[hh] = -1e30f;
        u32 off = 0;
        if (lane < deg) {
            int s = csr_src[start + lane];
            off = (u32)s * (u32)HIDC;
            if (H == 4) {
                float4 a4 = *(const float4*)(asrc + s * 4);
                v[0] = lk(a4.x + ad[0]);
                v[1 % H] = lk(a4.y + ad[1 % H]);
                v[2 % H] = lk(a4.z + ad[2 % H]);
                v[3 % H] = lk(a4.w + ad[3 % H]);
            } else {
                v[0] = lk(asrc[s] + ad[0]);
            }
        }
        float m[H];
#pragma unroll
        for (int hh = 0; hh < H; ++hh) m[hh] = v[hh];
#pragma unroll
        for (int o = 1; o < 64; o <<= 1)
#pragma unroll
            for (int hh = 0; hh < H; ++hh)
                m[hh] = fmaxf(m[hh], __shfl_xor(m[hh], o, 64));
        float w[H];
#pragma unroll
        for (int hh = 0; hh < H; ++hh) {
            w[hh] = __expf(v[hh] - m[hh]);
            wsum[hh] = w[hh];
        }
#pragma unroll
        for (int o = 1; o < 64; o <<= 1)
#pragma unroll
            for (int hh = 0; hh < H; ++hh)
                wsum[hh] += __shfl_xor(wsum[hh], o, 64);
        if (H == 4) {
            uint4 w0, w1;
            w0.x = off; w0.y = __float_as_uint(w[0]);
            w0.z = off; w0.w = __float_as_uint(w[1 % H]);
            w1.x = off; w1.y = __float_as_uint(w[2 % H]);
            w1.z = off; w1.w = __float_as_uint(w[3 % H]);
            *(uint4*)&s_ed[wid][lane * 4] = w0;
            *(uint4*)&s_ed[wid][lane * 4 + 2] = w1;
        } else {
            s_ed[wid][lane] = make_uint2(off, __float_as_uint(w[0]));
        }
        int j = 0;
        for (; j + 4 <= deg; j += 4) { GBODY(j) GBODY(j + 1) GBODY(j + 2) GBODY(j + 3) }
        for (; j < deg; ++j) GBODY(j)
    } else {
        float m[H];
#pragma unroll
        for (int hh = 0; hh < H; ++hh) m[hh] = -1e30f;
        for (int i = start + lane; i < end; i += 64) {
            int s = csr_src[i];
            if (H == 4) {
                float4 a4 = *(const float4*)(asrc + s * 4);
                m[0] = fmaxf(m[0], lk(a4.x + ad[0]));
                m[1 % H] = fmaxf(m[1 % H], lk(a4.y + ad[1 % H]));
                m[2 % H] = fmaxf(m[2 % H], lk(a4.z + ad[2 % H]));
                m[3 % H] = fmaxf(m[3 % H], lk(a4.w + ad[3 % H]));
            } else {
                m[0] = fmaxf(m[0], lk(asrc[s] + ad[0]));
            }
        }
#pragma unroll
        for (int o = 1; o < 64; o <<= 1)
#pragma unroll
            for (int hh = 0; hh < H; ++hh)
                m[hh] = fmaxf(m[hh], __shfl_xor(m[hh], o, 64));
#pragma unroll
        for (int hh = 0; hh < H; ++hh) wsum[hh] = 0.f;
        for (int base = start; base < end; base += 64) {
            int cnt = min(64, end - base);
            if (lane < cnt) {
                int s = csr_src[base + lane];
                u32 off = (u32)s * (u32)HIDC;
                if (H == 4) {
                    float4 a4 = *(const float4*)(asrc + s * 4);
                    float w0f = __expf(lk(a4.x + ad[0]) - m[0]);
                    float w1f = __expf(lk(a4.y + ad[1 % H]) - m[1 % H]);
                    float w2f = __expf(lk(a4.z + ad[2 % H]) - m[2 % H]);
                    float w3f = __expf(lk(a4.w + ad[3 % H]) - m[3 % H]);
                    wsum[0] += w0f; wsum[1 % H] += w1f;
                    wsum[2 % H] += w2f; wsum[3 % H] += w3f;
                    uint4 w0, w1;
                    w0.x = off; w0.y = __float_as_uint(w0f);
                    w0.z = off; w0.w = __float_as_uint(w1f);
                    w1.x = off; w1.y = __float_as_uint(w2f);
                    w1.z = off; w1.w = __float_as_uint(w3f);
                    *(uint4*)&s_ed[wid][lane * 4] = w0;
                    *(uint4*)&s_ed[wid][lane * 4 + 2] = w1;
                } else {
                    float wf = __expf(lk(asrc[s] + ad[0]) - m[0]);
                    wsum[0] += wf;
                    s_ed[wid][lane] = make_uint2(off, __float_as_uint(wf));
                }
            }
            int j = 0;
            for (; j + 4 <= cnt; j += 4) { GBODY(j) GBODY(j + 1) GBODY(j + 2) GBODY(j + 3) }
            for (; j < cnt; ++j) GBODY(j)
        }
#pragma unroll
        for (int o = 1; o < 64; o <<= 1)
#pragma unroll
            for (int hh = 0; hh < H; ++hh)
                wsum[hh] += __shfl_xor(wsum[hh], o, 64);
    }
#undef GBODY
    float sc = 1.f / (wsum[head] + 1e-16f);
    f32x2 sc2 = {sc, sc};
    acc01 *= sc2;
    acc23 *= sc2;
    uint2 o;
    o.x = pack2(acc01.x, acc01.y);
    o.y = pack2(acc23.x, acc23.y);
    ((uint2*)(agg + (size_t)n * HIDC))[lane] = o;
}

// ---------- BatchNorm stats (bf16 in, fp32 accumulate) ----------
__global__ __launch_bounds__(256)
void bn_stats_kernel(const u16* __restrict__ h, int N,
                     float* __restrict__ sum, float* __restrict__ sumsq) {
    int c = threadIdx.x;
    int r0 = blockIdx.x * 128;
    int rend = min(r0 + 128, N);
    float s = 0.f, q = 0.f;
    for (int r = r0; r < rend; ++r) {
        float v = b2f(h[(long)r * HIDC + c]);
        s += v;
        q += v * v;
    }
    atomicAdd(&sum[c], s);
    atomicAdd(&sumsq[c], q);
}

// ---------- pool with inline BN+relu; also writes out batch tail ----------
__global__ __launch_bounds__(256)
void pool_bn_kernel(const u16* __restrict__ h, const int* __restrict__ batch,
                    int N, const float* __restrict__ bnsum,
                    const float* __restrict__ bnsq,
                    const float* __restrict__ gamma,
                    const float* __restrict__ beta,
                    float* __restrict__ gsum, float* __restrict__ gcnt,
                    float* __restrict__ outTail) {
    int c = threadIdx.x;
    float invN = 1.f / (float)N;
    float mu = bnsum[c] * invN;
    float var = bnsq[c] * invN - mu * mu;
    float inv = rsqrtf(var + EPS_BN);
    float sc = gamma[c] * inv;
    float bi = beta[c] - mu * sc;
    int r0 = blockIdx.x * 128;
    int rend = min(r0 + 128, N);
    int curb = -1;
    float acc = 0.f;
    for (int r = r0; r < rend; ++r) {
        int b = batch[r];
        if (b != curb) {
            if (curb >= 0) atomicAdd(&gsum[curb * HIDC + c], acc);
            curb = b; acc = 0.f;
        }
        acc += fmaxf(fmaf(sc, b2f(h[(long)r * HIDC + c]), bi), 0.f);
    }
    if (curb >= 0) atomicAdd(&gsum[curb * HIDC + c], acc);
    if (c < 128 && r0 + c < rend) outTail[r0 + c] = (float)batch[r0 + c];
    if (c == 0) {
        int prev = -1; float cnt = 0.f;
        for (int r = r0; r < rend; ++r) {
            int b = batch[r];
            if (b != prev) {
                if (prev >= 0) atomicAdd(&gcnt[prev], cnt);
                prev = b; cnt = 0.f;
            }
            cnt += 1.f;
        }
        if (prev >= 0) atomicAdd(&gcnt[prev], cnt);
    }
}

// ---------- gmean + projection: gproj[b,c] = Σ_k gmean[b,k]*Wq1[256+k,c] --
__global__ __launch_bounds__(256)
void gmean_gproj_kernel(const float* __restrict__ gsum,
                        const float* __restrict__ gcnt,
                        const float* __restrict__ Wq1,
                        float* __restrict__ gproj) {
    int b = blockIdx.x, c = threadIdx.x;
    __shared__ float gm[HIDC];
    gm[c] = gsum[b * HIDC + c] / fmaxf(gcnt[b], 1.f);
    __syncthreads();
    float acc = 0.f;
    for (int k = 0; k < HIDC; ++k)
        acc = fmaf(gm[k], Wq1[(long)(HIDC + k) * HIDC + c], acc);
    gproj[b * HIDC + c] = acc;
}

extern "C" void kernel_launch(void* const* d_in, const int* in_sizes, int n_in,
                              void* d_out, int out_size, void* d_ws, size_t ws_size,
                              hipStream_t stream) {
    const float* x   = (const float*)d_in[0];
    const int*   ei  = (const int*)d_in[1];
    const int*   bat = (const int*)d_in[2];
    const float* W1  = (const float*)d_in[3];
    const float* as1 = (const float*)d_in[4];
    const float* ad1 = (const float*)d_in[5];
    const float* g1  = (const float*)d_in[7];
    const float* be1 = (const float*)d_in[8];
    const float* W2  = (const float*)d_in[9];
    const float* as2 = (const float*)d_in[10];
    const float* ad2 = (const float*)d_in[11];
    const float* g2  = (const float*)d_in[13];
    const float* be2 = (const float*)d_in[14];
    const float* Wq1 = (const float*)d_in[15];
    const float* bq1 = (const float*)d_in[16];
    const float* Wq2 = (const float*)d_in[17];
    const float* bq2 = (const float*)d_in[18];
    float* out = (float*)d_out;

    const int N = in_sizes[0] / F_IN;   // 50000
    const int E = in_sizes[1] / 2;      // 800000
    const int Etot = E + N;
    const int nb = (N + 255) / 256;

    const size_t hbytes = (size_t)N * HIDC * sizeof(u16);   // 25.6 MB (bf16)
    char* p = (char*)d_ws;
    auto alloc = [&](size_t sz) { char* q = p; p += (sz + 255) & ~(size_t)255; return q; };
    u16* BX   = (u16*)alloc((size_t)N * F_IN * sizeof(u16)); // bf16 x
    u8*  BH   = (u8*)alloc((size_t)N * HIDC);  // h1 -> h2 (fp8, 12.8 MB)
    u16* BA   = (u16*)alloc(hbytes);   // agg1 -> agg2 (bf16)
    u16* WT1  = (u16*)alloc((size_t)HIDC * F_IN * sizeof(u16));
    u16* WT2  = (u16*)alloc((size_t)HIDC * HIDC * sizeof(u16));
    u16* WQT  = (u16*)alloc((size_t)HIDC * HIDC * sizeof(u16));
    float* asrc = (float*)alloc((size_t)N * 4 * 4 * 2);      // asrc | adst
    float* adst = asrc + (size_t)N * 4;
    int* rowptr  = (int*)alloc((size_t)(N + 1) * 4);
    int* csr_src = (int*)alloc((size_t)Etot * 4);
    int* cur     = (int*)alloc((size_t)N * 4 * 2);           // deg | fill cursor
    int* cur2    = cur + N;
    int* part    = (int*)alloc((size_t)N * 4);
    int* bsum    = (int*)alloc((size_t)nb * 4);
    float* bnsum = (float*)alloc(HIDC * 4 * 2);              // bnsum | bnsq
    float* bnsq  = bnsum + HIDC;
    float* gsum  = (float*)alloc((NG * HIDC + NG) * 4);      // gsum | gcnt
    float* gcnt  = gsum + NG * HIDC;
    float* gproj = (float*)alloc(NG * HIDC * 4);

    dim3 gemmGrid((N + 31) / 32);        // 32 rows x 256 cols per block
    int edgeBlocks = (Etot + 255) / 256;
    int nodeBlocksW = (N + 3) / 4;
    int npair = N * F_IN / 2;
    int prepTotal = npair + F_IN * HIDC + 2 * HIDC * HIDC;

    // ===================== CSR build (once) ==============================
    hipMemsetAsync(cur, 0, (size_t)N * 4 * 2, stream);        // cur + cur2
    deg_kernel<<<edgeBlocks, 256, 0, stream>>>(ei, E, N, cur);
    scan_phase1<<<nb, 256, 0, stream>>>(cur, part, bsum, N);
    scan_phase2<<<1, 256, 0, stream>>>(bsum, nb);
    scan_phase3<<<nb, 256, 0, stream>>>(part, bsum, rowptr, N);
    fill_kernel<<<edgeBlocks, 256, 0, stream>>>(ei, E, N, rowptr, cur2, csr_src);

    // ===================== prep (1 dispatch) =============================
    prep_kernel<<<(prepTotal + 255) / 256, 256, 0, stream>>>(
        x, W1, W2, Wq1, (u32*)BX, WT1, WT2, WQT, npair);

    // ===================== Layer 1: GEMM(+alpha4) -> gather -> BN stats ==
    gemm_mfma_kernel<F_IN, 0><<<gemmGrid, 256, 0, stream>>>(
        BX, WT1, BH, N, nullptr, nullptr, nullptr, nullptr,
        as1, ad1, asrc, adst, nullptr, nullptr, nullptr, nullptr, nullptr, nullptr);
    gat_gather_kernel<4><<<nodeBlocksW, 256, 0, stream>>>(rowptr, csr_src, asrc, adst, BH, BA, N);
    hipMemsetAsync(bnsum, 0, HIDC * 4 * 2, stream);           // bnsum + bnsq
    bn_stats_kernel<<<(N + 127) / 128, 256, 0, stream>>>(BA, N, bnsum, bnsq);

    // ===================== Layer 2: GEMM(BN inline, +alpha1) -> gather ===
    gemm_mfma_kernel<HIDC, 1><<<gemmGrid, 256, 0, stream>>>(
        BA, WT2, BH, N, bnsum, bnsq, g1, be1,
        as2, ad2, asrc, adst, nullptr, nullptr, nullptr, nullptr, nullptr, nullptr);
    gat_gather_kernel<1><<<nodeBlocksW, 256, 0, stream>>>(rowptr, csr_src, asrc, adst, BH, BA, N);
    hipMemsetAsync(bnsum, 0, HIDC * 4 * 2, stream);
    bn_stats_kernel<<<(N + 127) / 128, 256, 0, stream>>>(BA, N, bnsum, bnsq);

    // ===================== Pool (BN inline, + batch tail) + projection ===
    hipMemsetAsync(gsum, 0, (NG * HIDC + NG) * 4, stream);    // gsum + gcnt
    pool_bn_kernel<<<(N + 127) / 128, 256, 0, stream>>>(
        BA, bat, N, bnsum, bnsq, g2, be2, gsum, gcnt, out + (size_t)N * 4);
    gmean_gproj_kernel<<<NG, HIDC, 0, stream>>>(gsum, gcnt, Wq1, gproj);

    // ===================== Head: GEMM(BN inline, fused q, direct store) ==
    gemm_mfma_kernel<HIDC, 2><<<gemmGrid, 256, 0, stream>>>(
        BA, WQT, nullptr, N, bnsum, bnsq, g2, be2,
        nullptr, nullptr, nullptr, nullptr, gproj, bat, bq1, Wq2, bq2, out);
}